// Round 4
// baseline (1391.979 us; speedup 1.0000x reference)
//
#include <hip/hip_runtime.h>
#include <math.h>

#define BB 2
#define SS 2048
#define HH 768
#define NHH 12
#define LL 4
#define DD 64
#define WW 128
#define GG 16
#define PP 128
#define NLL 3
#define FF 3072
#define NCH 8   // key chunks for global-attention flash-decoding split
#define SK 4    // split-K factor for the N=768 GEMMs

typedef __bf16 bf16x8 __attribute__((ext_vector_type(8)));
typedef __bf16 bf16x4 __attribute__((ext_vector_type(4)));
typedef float f32x4 __attribute__((ext_vector_type(4)));

// Async global->LDS direct load, 16B per lane. LDS dest must be
// wave-uniform base + lane*16 (linear layout).
#define GLL16(gp, lp) __builtin_amdgcn_global_load_lds( \
    (__attribute__((address_space(1))) void*)(gp),      \
    (__attribute__((address_space(3))) void*)(lp), 16, 0, 0)

// ---------------------------------------------------------------------------
// Embedding gather: x[row,:] = emb[ids[row],:], plus bf16 copy.
__global__ __launch_bounds__(256) void embed_kernel(const int* __restrict__ ids,
    const float* __restrict__ emb, float* __restrict__ x, __bf16* __restrict__ xb)
{
    int row = blockIdx.x;
    int id = ids[row];
    const float* e = emb + (size_t)id * HH;
    float* xp = x + (size_t)row * HH;
    __bf16* xbp = xb + (size_t)row * HH;
    for (int i = threadIdx.x; i < HH; i += 256) {
        float v = e[i];
        xp[i] = v;
        xbp[i] = (__bf16)v;
    }
}

// ---------------------------------------------------------------------------
// Pack per-layer q,k,v biases into [L][3*H]
__global__ __launch_bounds__(256) void pack_bias_kernel(const float* __restrict__ bq,
    const float* __restrict__ bk, const float* __restrict__ bv, float* __restrict__ dst)
{
    int l = blockIdx.x;
    for (int i = threadIdx.x; i < HH; i += 256) {
        dst[(size_t)l * 3 * HH + i]          = bq[(size_t)l * HH + i];
        dst[(size_t)l * 3 * HH + HH + i]     = bk[(size_t)l * HH + i];
        dst[(size_t)l * 3 * HH + 2 * HH + i] = bv[(size_t)l * HH + i];
    }
}

// ---------------------------------------------------------------------------
// Transpose + fp32->bf16: src [K][N] fp32 -> dst [N][K] bf16. blockIdx.z = layer.
__global__ __launch_bounds__(256) void transpose_bf16_kernel(const float* __restrict__ src,
    __bf16* __restrict__ dst, int K, int N, size_t src_ls, size_t dst_ls)
{
    int l = blockIdx.z;
    src += (size_t)l * src_ls;
    dst += (size_t)l * dst_ls;
    __shared__ float t[32][33];
    int tx = threadIdx.x & 31, ty = threadIdx.x >> 5;  // 32 x 8
    int n0 = blockIdx.x * 32, k0 = blockIdx.y * 32;
    for (int i = ty; i < 32; i += 8)
        t[i][tx] = src[(size_t)(k0 + i) * N + n0 + tx];
    __syncthreads();
    for (int i = ty; i < 32; i += 8)
        dst[(size_t)(n0 + i) * K + k0 + tx] = (__bf16)t[tx][i];
}

// ---------------------------------------------------------------------------
// bf16 MFMA GEMM: C[M,N] = epi(A[M,K] @ Bt[N,K]^T + bias)
// 128x128 tile, BK=64, single-buffered 32KB LDS, 4 waves (2x2 of 64x64),
// 16x16x32 MFMA, global_load_lds staging with T2 XOR swizzle via pre-swizzled
// GLOBAL source (LDS linear; read addr same XOR). T1 XCD-aware block swizzle
// (bijective) on the flattened x,y grid for L2 panel locality.
// blockIdx.z = split-K chunk. epi: 3 = gelu bf16 | 4 = qkv bf16 | 5 = raw partial
__global__ __launch_bounds__(256) void mfma_gemm(
    const __bf16* __restrict__ A, const __bf16* __restrict__ Bt,
    const float* __restrict__ bias, void* __restrict__ outv,
    void* __restrict__ outb, int M, int N, int K, int epi, float scale)
{
    __shared__ __align__(16) __bf16 As[128 * 64];   // 16 KB
    __shared__ __align__(16) __bf16 Bs[128 * 64];   // 16 KB
    int tid = threadIdx.x;

    // T1: XCD-aware bijective block swizzle (hardware round-robins the
    // linear id across 8 XCDs; give each XCD a contiguous tile chunk).
    int nwg = gridDim.x * gridDim.y;
    int orig = blockIdx.y * gridDim.x + blockIdx.x;
    int qq = nwg >> 3, rr = nwg & 7;
    int xcd = orig & 7, off = orig >> 3;
    int swz = (xcd < rr ? xcd * (qq + 1) : rr * (qq + 1) + (xcd - rr) * qq) + off;
    int tileM = (swz / gridDim.x) * 128;
    int tileN = (swz % gridDim.x) * 128;

    int zk = blockIdx.z;
    int kpb = K / gridDim.z;          // K per block (multiple of 64)
    int kbeg = zk * kpb;
    int wave = tid >> 6, lane = tid & 63;
    int wm = (wave >> 1) * 64, wn = (wave & 1) * 64;
    int lr = lane & 15, quad = lane >> 4;

    // Staging map (round r=0..3): idx = r*256+tid; LDS 16B-slot = idx
    // (linear). row = idx>>3, slot c' = idx&7; source chunk c = c'^(row&7).
    int srow = tid >> 3;                    // +32 per round
    int sc   = (tid & 7) ^ (srow & 7);      // round-invariant (32%8==0)
    const __bf16* Ap = A  + (size_t)(tileM + srow) * K + kbeg + sc * 8;
    const __bf16* Bp = Bt + (size_t)(tileN + srow) * K + kbeg + sc * 8;

    f32x4 acc[4][4] = {};
    int rsw = lr & 7;                       // (row & 7) for fragment rows
    int nsteps = kpb >> 6;

    for (int t = 0; t < nsteps; t++) {
        __syncthreads();                    // previous tile's reads done
        #pragma unroll
        for (int r = 0; r < 4; r++) {
            GLL16(Ap + t * 64 + (size_t)(r * 32) * K, As + (r * 256 + tid) * 8);
            GLL16(Bp + t * 64 + (size_t)(r * 32) * K, Bs + (r * 256 + tid) * 8);
        }
        __syncthreads();                    // drains vmcnt(0): tile visible
        #pragma unroll
        for (int ks = 0; ks < 2; ks++) {
            int ca = ((ks * 4 + quad) ^ rsw) * 8;   // swizzled chunk
            bf16x8 af[4], bfr[4];
            #pragma unroll
            for (int i = 0; i < 4; i++) {
                af[i]  = *(const bf16x8*)&As[(wm + i * 16 + lr) * 64 + ca];
                bfr[i] = *(const bf16x8*)&Bs[(wn + i * 16 + lr) * 64 + ca];
            }
            #pragma unroll
            for (int mi = 0; mi < 4; mi++)
                #pragma unroll
                for (int ni = 0; ni < 4; ni++)
                    acc[mi][ni] = __builtin_amdgcn_mfma_f32_16x16x32_bf16(
                        af[mi], bfr[ni], acc[mi][ni], 0, 0, 0);
        }
    }

    int zq = (epi == 4) ? tileN / HH : 0;
    #pragma unroll
    for (int mi = 0; mi < 4; mi++) {
        #pragma unroll
        for (int reg = 0; reg < 4; reg++) {
            int row = tileM + wm + mi * 16 + quad * 4 + reg;
            #pragma unroll
            for (int ni = 0; ni < 4; ni++) {
                int col = tileN + wn + ni * 16 + lr;
                if (epi == 5) {
                    // raw split-K partial (bias/res applied in ln_sum)
                    ((float*)outv)[((size_t)zk * M + row) * HH + col] =
                        acc[mi][ni][reg];
                } else if (epi == 3) {
                    float v = acc[mi][ni][reg] + bias[col];
                    float t = 0.7978845608028654f * (v + 0.044715f * v * v * v);
                    float e = __expf(2.f * t);
                    v = 0.5f * v * (2.f - 2.f / (e + 1.f));
                    ((__bf16*)outv)[(size_t)row * N + col] = (__bf16)v;
                } else {
                    // epi 4: qkv split, bf16 only (q gets scale)
                    float v = acc[mi][ni][reg] + bias[col];
                    if (zq == 0) v *= scale;
                    size_t idx = ((size_t)zq * M + row) * HH + (col - zq * HH);
                    ((__bf16*)outb)[idx] = (__bf16)v;
                }
            }
        }
    }
}

// ---------------------------------------------------------------------------
// LayerNorm over H with fused split-K reduction + bias + residual:
// v = sum_p part[p][row] + bias + res[row]; out = LN(v)*g+b (fp32 + bf16).
// Safe for res==out (each thread rewrites only elements it read).
__global__ __launch_bounds__(256) void ln_sum_kernel(const float* __restrict__ part,
    const float* __restrict__ res, const float* __restrict__ bvec,
    const float* __restrict__ g, const float* __restrict__ b,
    float* __restrict__ out, __bf16* __restrict__ outb)
{
    int row = blockIdx.x;
    int tid = threadIdx.x;
    const size_t slab = (size_t)BB * SS * HH;
    const float* p0 = part + (size_t)row * HH;
    __shared__ float red[256];
    float v[3];
    #pragma unroll
    for (int j = 0; j < 3; j++) {
        int i = tid + j * 256;
        float s = p0[i] + p0[slab + i] + p0[2 * slab + i] + p0[3 * slab + i];
        v[j] = s + bvec[i] + res[(size_t)row * HH + i];
    }
    float s = v[0] + v[1] + v[2];
    red[tid] = s; __syncthreads();
    for (int st = 128; st > 0; st >>= 1) { if (tid < st) red[tid] += red[tid + st]; __syncthreads(); }
    float mean = red[0] / HH;
    __syncthreads();
    float vs = 0.f;
    #pragma unroll
    for (int j = 0; j < 3; j++) { float d = v[j] - mean; vs += d * d; }
    red[tid] = vs; __syncthreads();
    for (int st = 128; st > 0; st >>= 1) { if (tid < st) red[tid] += red[tid + st]; __syncthreads(); }
    float rstd = rsqrtf(red[0] / HH + 1e-5f);
    #pragma unroll
    for (int j = 0; j < 3; j++) {
        int i = tid + j * 256;
        float o = (v[j] - mean) * rstd * g[i] + b[i];
        out[(size_t)row * HH + i] = o;
        outb[(size_t)row * HH + i] = (__bf16)o;
    }
}

// ---------------------------------------------------------------------------
// MFMA flash band+global-key attention, bf16 inputs, 128-query blocks.
// Grid (NHH, SS/128, BB), 512 threads = 8 waves; wave w owns queries
// [c0+16w, c0+16w+16): softmax state is wave-local. K/V tiles staged once
// serve all 128 queries; waves skip fully-masked band tiles.
__global__ __launch_bounds__(512) void band_attn_mfma(const __bf16* __restrict__ q,
    const __bf16* __restrict__ kg, const __bf16* __restrict__ vg, __bf16* __restrict__ ob)
{
    __shared__ __align__(16) __bf16 Qs[128][72];
    __shared__ __align__(16) __bf16 Ks[64][72];
    __shared__ __align__(16) __bf16 Vt[64][72];    // Vt[d][key]
    __shared__ __align__(16) __bf16 Pw[128][72];   // P[q_local][key], wave strips

    const int h  = blockIdx.x;
    const int c0 = blockIdx.y * 128;
    const int b  = blockIdx.z;
    const int tid  = threadIdx.x;
    const int wave = tid >> 6, lane = tid & 63;
    const int lr = lane & 15, quad = lane >> 4;

    // ---- stage Q tile rows c0..c0+127 (bf16 direct)
    {
        int r = tid >> 2, dq = (tid & 3) * 16;
        const __bf16* qp = q + (((size_t)b * SS + c0 + r) * NHH + h) * DD + dq;
        *(bf16x8*)&Qs[r][dq]     = *(const bf16x8*)qp;
        *(bf16x8*)&Qs[r][dq + 8] = *(const bf16x8*)(qp + 8);
    }
    __syncthreads();
    bf16x8 aq0 = *(const bf16x8*)&Qs[wave * 16 + lr][quad * 8];
    bf16x8 aq1 = *(const bf16x8*)&Qs[wave * 16 + lr][32 + quad * 8];

    f32x4 O[4] = {};
    f32x4 m_run = {-1e30f, -1e30f, -1e30f, -1e30f};
    f32x4 l_run = {0.f, 0.f, 0.f, 0.f};

    int lo = c0 - WW; if (lo < GG) lo = GG;
    int hi = c0 + 127 + WW; if (hi > SS - 1) hi = SS - 1;
    int nband = (hi - lo + 64) / 64;
    const int qw0 = c0 + wave * 16;          // wave's first query
    const int q0 = qw0 + quad * 4;           // lane's first query row

    for (int t = 0; t <= nband; t++) {
        int kbase = (t == 0) ? 0 : lo + (t - 1) * 64;
        int kend  = (t == 0) ? GG : (kbase + 64 < hi + 1 ? kbase + 64 : hi + 1);

        __syncthreads();   // close previous tile's LDS reads before restaging
        {   // K rows: 512 threads, one bf16x8 each
            int r = tid >> 3, dq = (tid & 7) * 8;
            int kpos = kbase + r;
            if (kpos < kend) {
                const __bf16* kp = kg + (((size_t)b * SS + kpos) * NHH + h) * DD + dq;
                *(bf16x8*)&Ks[r][dq] = *(const bf16x8*)kp;
            }
            // stale rows are masked out at the score level
        }
        {   // V transposed: thread group (tid>>6) stages dims [8g, 8g+8)
            int r2 = tid & 63, dg = (tid >> 6) * 8;
            int kpos = kbase + r2;
            if (kpos < kend) {
                const __bf16* vp = vg + (((size_t)b * SS + kpos) * NHH + h) * DD + dg;
                bf16x8 f0 = *(const bf16x8*)vp;
                #pragma unroll
                for (int u = 0; u < 8; u++) Vt[dg + u][r2] = f0[u];
            } else {
                #pragma unroll
                for (int u = 0; u < 8; u++) Vt[dg + u][r2] = (__bf16)0.f;
            }
        }
        __syncthreads();

        // wave-level skip: band tile entirely outside this wave's window
        if (t > 0 && (kbase > qw0 + 15 + WW || kbase + 63 < qw0 - WW))
            continue;

        // ---- S = Q K^T  (16q x 64key per wave)
        f32x4 S[4] = {};
        #pragma unroll
        for (int nt = 0; nt < 4; nt++) {
            bf16x8 k0v = *(const bf16x8*)&Ks[nt * 16 + lr][quad * 8];
            bf16x8 k1v = *(const bf16x8*)&Ks[nt * 16 + lr][32 + quad * 8];
            S[nt] = __builtin_amdgcn_mfma_f32_16x16x32_bf16(aq0, k0v, S[nt], 0, 0, 0);
            S[nt] = __builtin_amdgcn_mfma_f32_16x16x32_bf16(aq1, k1v, S[nt], 0, 0, 0);
        }
        // ---- mask
        bool glob = (t == 0);
        #pragma unroll
        for (int nt = 0; nt < 4; nt++) {
            int key = kbase + nt * 16 + lr;
            #pragma unroll
            for (int r = 0; r < 4; r++) {
                int dd = key - (q0 + r);
                bool ok = (key < kend) && (glob || (dd <= WW && dd >= -WW));
                if (!ok) S[nt][r] = -1e9f;
            }
        }
        // ---- online softmax (rows live in 16-lane groups)
        float al[4];
        #pragma unroll
        for (int r = 0; r < 4; r++) {
            float m = fmaxf(fmaxf(S[0][r], S[1][r]), fmaxf(S[2][r], S[3][r]));
            m = fmaxf(m, __shfl_xor(m, 1));
            m = fmaxf(m, __shfl_xor(m, 2));
            m = fmaxf(m, __shfl_xor(m, 4));
            m = fmaxf(m, __shfl_xor(m, 8));
            float mo = m_run[r];
            float mn = fmaxf(mo, m);
            m_run[r] = mn;
            al[r] = __expf(mo - mn);
        }
        #pragma unroll
        for (int nt = 0; nt < 4; nt++)
            #pragma unroll
            for (int r = 0; r < 4; r++)
                S[nt][r] = __expf(S[nt][r] - m_run[r]);
        #pragma unroll
        for (int r = 0; r < 4; r++) {
            float s = S[0][r] + S[1][r] + S[2][r] + S[3][r];
            s += __shfl_xor(s, 1);
            s += __shfl_xor(s, 2);
            s += __shfl_xor(s, 4);
            s += __shfl_xor(s, 8);
            l_run[r] = l_run[r] * al[r] + s;
            O[0][r] *= al[r]; O[1][r] *= al[r]; O[2][r] *= al[r]; O[3][r] *= al[r];
        }
        // ---- P -> bf16 via per-wave LDS strip
        #pragma unroll
        for (int nt = 0; nt < 4; nt++)
            #pragma unroll
            for (int r = 0; r < 4; r++)
                Pw[wave * 16 + quad * 4 + r][nt * 16 + lr] = (__bf16)S[nt][r];
        asm volatile("s_waitcnt lgkmcnt(0)" ::: "memory");  // intra-wave
        bf16x8 pa0 = *(const bf16x8*)&Pw[wave * 16 + lr][quad * 8];
        bf16x8 pa1 = *(const bf16x8*)&Pw[wave * 16 + lr][32 + quad * 8];
        // ---- O += P V
        #pragma unroll
        for (int nt = 0; nt < 4; nt++) {
            bf16x8 v0v = *(const bf16x8*)&Vt[nt * 16 + lr][quad * 8];
            bf16x8 v1v = *(const bf16x8*)&Vt[nt * 16 + lr][32 + quad * 8];
            O[nt] = __builtin_amdgcn_mfma_f32_16x16x32_bf16(pa0, v0v, O[nt], 0, 0, 0);
            O[nt] = __builtin_amdgcn_mfma_f32_16x16x32_bf16(pa1, v1v, O[nt], 0, 0, 0);
        }
    }

    // ---- epilogue: O / l
    #pragma unroll
    for (int r = 0; r < 4; r++) {
        int qg = q0 + r;
        float invl = 1.f / l_run[r];
        #pragma unroll
        for (int nt = 0; nt < 4; nt++) {
            int d = nt * 16 + lr;
            ob[(((size_t)b * SS + qg) * NHH + h) * DD + d] = (__bf16)(O[nt][r] * invl);
        }
    }
}

// ---------------------------------------------------------------------------
// Global-query attention pass 1 (flash-decoding split), bf16 inputs.
#define GP_STRIDE (GG * DD + 2 * GG)
__global__ __launch_bounds__(256) void global_attn_pass1(const __bf16* __restrict__ q,
    const __bf16* __restrict__ k, const __bf16* __restrict__ v, float* __restrict__ part)
{
    __shared__ float Qs[GG][68];
    __shared__ float Kt[64][68];
    __shared__ float Vs[64][68];
    __shared__ float Ssc[64][17];
    __shared__ float m_sh[GG], l_sh[GG], al_sh[GG];

    int ch = blockIdx.x, h = blockIdx.y, b = blockIdx.z;
    int tid = threadIdx.x;
    int q_i = tid >> 4;   // query 0..15
    int g_i = tid & 15;   // group 0..15

    {
        const __bf16* qp = q + (((size_t)b * SS + q_i) * NHH + h) * DD + g_i * 4;
        bf16x4 t4 = *(const bf16x4*)qp;
        Qs[q_i][g_i * 4 + 0] = (float)t4[0];
        Qs[q_i][g_i * 4 + 1] = (float)t4[1];
        Qs[q_i][g_i * 4 + 2] = (float)t4[2];
        Qs[q_i][g_i * 4 + 3] = (float)t4[3];
    }
    if (tid < GG) { m_sh[tid] = -1e30f; l_sh[tid] = 0.f; }

    float O[4] = {0.f, 0.f, 0.f, 0.f};

    for (int t = 0; t < 4; t++) {
        int kbase = ch * 256 + t * 64;
        __syncthreads();
        {
            int r = tid >> 2, dq = (tid & 3) * 16;
            const __bf16* kp = k + (((size_t)b * SS + kbase + r) * NHH + h) * DD + dq;
            const __bf16* vp = v + (((size_t)b * SS + kbase + r) * NHH + h) * DD + dq;
            bf16x8 k0 = *(const bf16x8*)kp, k1 = *(const bf16x8*)(kp + 8);
            bf16x8 v0 = *(const bf16x8*)vp, v1 = *(const bf16x8*)(vp + 8);
            #pragma unroll
            for (int u = 0; u < 8; u++) {
                Kt[dq + u][r]     = (float)k0[u];
                Kt[dq + 8 + u][r] = (float)k1[u];
                Vs[r][dq + u]     = (float)v0[u];
                Vs[r][dq + 8 + u] = (float)v1[u];
            }
        }
        __syncthreads();

        float sc[4] = {0.f, 0.f, 0.f, 0.f};
        for (int d = 0; d < 64; d++) {
            float qv = Qs[q_i][d];
            #pragma unroll
            for (int j = 0; j < 4; j++) sc[j] += qv * Kt[d][g_i * 4 + j];
        }
        #pragma unroll
        for (int j = 0; j < 4; j++) Ssc[g_i * 4 + j][q_i] = sc[j];
        __syncthreads();

        if (tid < GG) {
            float mo = m_sh[tid], mx = mo;
            for (int kk = 0; kk < 64; kk++) mx = fmaxf(mx, Ssc[kk][tid]);
            float al = __expf(mo - mx);
            al_sh[tid] = al; m_sh[tid] = mx;
            float s = 0.f;
            for (int kk = 0; kk < 64; kk++) {
                float p = __expf(Ssc[kk][tid] - mx);
                Ssc[kk][tid] = p;
                s += p;
            }
            l_sh[tid] = l_sh[tid] * al + s;
        }
        __syncthreads();

        float al = al_sh[q_i];
        #pragma unroll
        for (int j = 0; j < 4; j++) O[j] *= al;
        for (int kk = 0; kk < 64; kk++) {
            float p = Ssc[kk][q_i];
            #pragma unroll
            for (int j = 0; j < 4; j++) O[j] += p * Vs[kk][g_i * 4 + j];
        }
    }
    __syncthreads();

    size_t base = (((size_t)b * NHH + h) * NCH + ch) * GP_STRIDE;
    #pragma unroll
    for (int j = 0; j < 4; j++) part[base + q_i * DD + g_i * 4 + j] = O[j];
    if (tid < GG) {
        part[base + GG * DD + tid] = m_sh[tid];
        part[base + GG * DD + GG + tid] = l_sh[tid];
    }
}

// ---------------------------------------------------------------------------
// Global-query attention pass 2: merge NCH chunk partials, write bf16 rows.
__global__ __launch_bounds__(64) void global_attn_combine(const float* __restrict__ part,
    __bf16* __restrict__ ob)
{
    int g = blockIdx.x, h = blockIdx.y, b = blockIdx.z;
    int d = threadIdx.x;
    size_t base0 = (((size_t)b * NHH + h) * NCH) * GP_STRIDE;
    float m[NCH], l[NCH], M = -1e30f;
    #pragma unroll
    for (int ch = 0; ch < NCH; ch++) {
        m[ch] = part[base0 + ch * GP_STRIDE + GG * DD + g];
        l[ch] = part[base0 + ch * GP_STRIDE + GG * DD + GG + g];
        M = fmaxf(M, m[ch]);
    }
    float L = 0.f, o = 0.f;
    #pragma unroll
    for (int ch = 0; ch < NCH; ch++) {
        float w = __expf(m[ch] - M);
        L += w * l[ch];
        o += w * part[base0 + ch * GP_STRIDE + g * DD + d];
    }
    ob[(((size_t)b * SS + g) * NHH + h) * DD + d] = (__bf16)(o / L);
}

// ---------------------------------------------------------------------------
// Pair head: out[row,:] = concat(x[b,i,:], x[b,j,:]) @ Wh + bh
__global__ __launch_bounds__(256) void pair_head_kernel(const float* __restrict__ x,
    const int* __restrict__ pairs, const float* __restrict__ Wh,
    const float* __restrict__ bh, float* __restrict__ out)
{
    int row = blockIdx.x;
    int b = row / PP;
    int i = pairs[row * 2 + 0];
    int j = pairs[row * 2 + 1];
    const float* xi = x + ((size_t)b * SS + i) * HH;
    const float* xj = x + ((size_t)b * SS + j) * HH;
    float acc[NLL] = {};
    for (int e = threadIdx.x; e < 2 * HH; e += 256) {
        float val = (e < HH) ? xi[e] : xj[e - HH];
        #pragma unroll
        for (int c = 0; c < NLL; c++) acc[c] += val * Wh[e * NLL + c];
    }
    __shared__ float red[NLL * 256];
    #pragma unroll
    for (int c = 0; c < NLL; c++) red[c * 256 + threadIdx.x] = acc[c];
    __syncthreads();
    for (int st = 128; st > 0; st >>= 1) {
        if (threadIdx.x < st)
            #pragma unroll
            for (int c = 0; c < NLL; c++)
                red[c * 256 + threadIdx.x] += red[c * 256 + threadIdx.x + st];
        __syncthreads();
    }
    if (threadIdx.x < NLL) out[row * NLL + threadIdx.x] = red[threadIdx.x * 256] + bh[threadIdx.x];
}

// ---------------------------------------------------------------------------
extern "C" void kernel_launch(void* const* d_in, const int* in_sizes, int n_in,
                              void* d_out, int out_size, void* d_ws, size_t ws_size,
                              hipStream_t stream)
{
    const int*   input_ids    = (const int*)d_in[0];
    const int*   pair_indices = (const int*)d_in[1];
    const float* emb   = (const float*)d_in[2];
    const float* Wq    = (const float*)d_in[3];
    const float* bq    = (const float*)d_in[4];
    const float* Wk    = (const float*)d_in[5];
    const float* bk    = (const float*)d_in[6];
    const float* Wv    = (const float*)d_in[7];
    const float* bv    = (const float*)d_in[8];
    const float* Wo    = (const float*)d_in[9];
    const float* bo    = (const float*)d_in[10];
    const float* ln1_g = (const float*)d_in[11];
    const float* ln1_b = (const float*)d_in[12];
    const float* Wf1   = (const float*)d_in[13];
    const float* bf1   = (const float*)d_in[14];
    const float* Wf2   = (const float*)d_in[15];
    const float* bf2   = (const float*)d_in[16];
    const float* ln2_g = (const float*)d_in[17];
    const float* ln2_b = (const float*)d_in[18];
    const float* Wh    = (const float*)d_in[19];
    const float* bh    = (const float*)d_in[20];

    const size_t R = (size_t)BB * SS;
    const size_t LWS = 4 * (size_t)HH * HH + 2 * (size_t)HH * FF;

    char* w = (char*)d_ws;
    float* x      = (float*)w;  w += R * HH * 4;
    float* t1     = (float*)w;  w += (size_t)SK * R * HH * 4;   // split-K partials
    __bf16* qkv_bf = (__bf16*)w; w += 3 * R * HH * 2;
    __bf16* x_bf  = (__bf16*)w; w += R * HH * 2;
    __bf16* o_bf  = (__bf16*)w; w += R * HH * 2;
    __bf16* hb_bf = (__bf16*)w; w += R * FF * 2;
    float* bias_qkv = (float*)w; w += LL * 3 * HH * 4;
    float* gpart  = (float*)w;  w += (size_t)BB * NHH * NCH * GP_STRIDE * 4;
    __bf16* Wbf   = (__bf16*)w; w += LL * LWS * 2;
    __bf16* qb = qkv_bf;
    __bf16* kb = qkv_bf + R * HH;
    __bf16* vb = qkv_bf + 2 * R * HH;

    pack_bias_kernel<<<dim3(LL), 256, 0, stream>>>(bq, bk, bv, bias_qkv);
    size_t hh = (size_t)HH * HH, hf = (size_t)HH * FF;
    transpose_bf16_kernel<<<dim3(HH/32, HH/32, LL), 256, 0, stream>>>(Wq, Wbf,            HH, HH, hh, LWS);
    transpose_bf16_kernel<<<dim3(HH/32, HH/32, LL), 256, 0, stream>>>(Wk, Wbf + hh,       HH, HH, hh, LWS);
    transpose_bf16_kernel<<<dim3(HH/32, HH/32, LL), 256, 0, stream>>>(Wv, Wbf + 2 * hh,   HH, HH, hh, LWS);
    transpose_bf16_kernel<<<dim3(HH/32, HH/32, LL), 256, 0, stream>>>(Wo, Wbf + 3 * hh,   HH, HH, hh, LWS);
    transpose_bf16_kernel<<<dim3(FF/32, HH/32, LL), 256, 0, stream>>>(Wf1, Wbf + 4 * hh,  HH, FF, hf, LWS);
    transpose_bf16_kernel<<<dim3(HH/32, FF/32, LL), 256, 0, stream>>>(Wf2, Wbf + 4 * hh + hf, FF, HH, hf, LWS);

    embed_kernel<<<dim3((int)R), 256, 0, stream>>>(input_ids, emb, x, x_bf);

    for (int l = 0; l < LL; l++) {
        __bf16* Wl = Wbf + (size_t)l * LWS;
        const float* lbo  = bo  + (size_t)l * HH;
        const float* lg1  = ln1_g + (size_t)l * HH;  const float* lb1 = ln1_b + (size_t)l * HH;
        const float* lbf1 = bf1 + (size_t)l * FF;
        const float* lbf2 = bf2 + (size_t)l * HH;
        const float* lg2  = ln2_g + (size_t)l * HH;  const float* lb2 = ln2_b + (size_t)l * HH;

        // QKV: bf16 outputs only (q pre-scaled)
        mfma_gemm<<<dim3(3 * HH / 128, R / 128, 1), 256, 0, stream>>>(
            x_bf, Wl, bias_qkv + (size_t)l * 3 * HH, nullptr, qkv_bf,
            (int)R, 3 * HH, HH, 4, 0.125f);

        band_attn_mfma<<<dim3(NHH, SS / 128, BB), 512, 0, stream>>>(qb, kb, vb, o_bf);
        global_attn_pass1<<<dim3(NCH, NHH, BB), 256, 0, stream>>>(qb, kb, vb, gpart);
        global_attn_combine<<<dim3(GG, NHH, BB), 64, 0, stream>>>(gpart, o_bf);

        // attn-out: split-K partials -> ln_sum (adds bo + residual x)
        mfma_gemm<<<dim3(HH / 128, R / 128, SK), 256, 0, stream>>>(
            o_bf, Wl + 3 * hh, nullptr, t1, nullptr, (int)R, HH, HH, 5, 0.f);
        ln_sum_kernel<<<dim3((int)R), 256, 0, stream>>>(t1, x, lbo, lg1, lb1, x, x_bf);

        mfma_gemm<<<dim3(FF / 128, R / 128, 1), 256, 0, stream>>>(
            x_bf, Wl + 4 * hh, lbf1, hb_bf, nullptr, (int)R, FF, HH, 3, 0.f);

        // FF2: split-K partials -> ln_sum (adds bf2 + residual x)
        mfma_gemm<<<dim3(HH / 128, R / 128, SK), 256, 0, stream>>>(
            hb_bf, Wl + 4 * hh + hf, nullptr, t1, nullptr, (int)R, HH, FF, 5, 0.f);
        ln_sum_kernel<<<dim3((int)R), 256, 0, stream>>>(t1, x, lbf2, lg2, lb2, x, x_bf);
    }

    pair_head_kernel<<<dim3(BB * PP), 256, 0, stream>>>(x, pair_indices, Wh, bh, (float*)d_out);
}

// Round 5
// 1206.864 us; speedup vs baseline: 1.1534x; 1.1534x over previous
//
#include <hip/hip_runtime.h>
#include <math.h>

#define BB 2
#define SS 2048
#define HH 768
#define NHH 12
#define LL 4
#define DD 64
#define WW 128
#define GG 16
#define PP 128
#define NLL 3
#define FF 3072
#define NCH 8    // key chunks for global-attention flash-decoding split
#define NQB 16   // band query blocks per (h,b) = SS/128

typedef __bf16 bf16x8 __attribute__((ext_vector_type(8)));
typedef __bf16 bf16x4 __attribute__((ext_vector_type(4)));
typedef float f32x4 __attribute__((ext_vector_type(4)));

// Async global->LDS direct load, 16B per lane. LDS dest must be
// wave-uniform base + lane*16 (linear layout).
#define GLL16(gp, lp) __builtin_amdgcn_global_load_lds( \
    (__attribute__((address_space(1))) void*)(gp),      \
    (__attribute__((address_space(3))) void*)(lp), 16, 0, 0)

// ---------------------------------------------------------------------------
// Embedding gather: x[row,:] = emb[ids[row],:], plus bf16 copy.
__global__ __launch_bounds__(256) void embed_kernel(const int* __restrict__ ids,
    const float* __restrict__ emb, float* __restrict__ x, __bf16* __restrict__ xb)
{
    int row = blockIdx.x;
    int id = ids[row];
    const float* e = emb + (size_t)id * HH;
    float* xp = x + (size_t)row * HH;
    __bf16* xbp = xb + (size_t)row * HH;
    for (int i = threadIdx.x; i < HH; i += 256) {
        float v = e[i];
        xp[i] = v;
        xbp[i] = (__bf16)v;
    }
}

// ---------------------------------------------------------------------------
// Pack per-layer q,k,v biases into [L][3*H]
__global__ __launch_bounds__(256) void pack_bias_kernel(const float* __restrict__ bq,
    const float* __restrict__ bk, const float* __restrict__ bv, float* __restrict__ dst)
{
    int l = blockIdx.x;
    for (int i = threadIdx.x; i < HH; i += 256) {
        dst[(size_t)l * 3 * HH + i]          = bq[(size_t)l * HH + i];
        dst[(size_t)l * 3 * HH + HH + i]     = bk[(size_t)l * HH + i];
        dst[(size_t)l * 3 * HH + 2 * HH + i] = bv[(size_t)l * HH + i];
    }
}

// ---------------------------------------------------------------------------
// Transpose + fp32->bf16: src [K][N] fp32 -> dst [N][K] bf16. blockIdx.z = layer.
__global__ __launch_bounds__(256) void transpose_bf16_kernel(const float* __restrict__ src,
    __bf16* __restrict__ dst, int K, int N, size_t src_ls, size_t dst_ls)
{
    int l = blockIdx.z;
    src += (size_t)l * src_ls;
    dst += (size_t)l * dst_ls;
    __shared__ float t[32][33];
    int tx = threadIdx.x & 31, ty = threadIdx.x >> 5;  // 32 x 8
    int n0 = blockIdx.x * 32, k0 = blockIdx.y * 32;
    for (int i = ty; i < 32; i += 8)
        t[i][tx] = src[(size_t)(k0 + i) * N + n0 + tx];
    __syncthreads();
    for (int i = ty; i < 32; i += 8)
        dst[(size_t)(n0 + i) * K + k0 + tx] = (__bf16)t[tx][i];
}

// ---------------------------------------------------------------------------
// bf16 MFMA GEMM: C[M,N] = epi(A[M,K] @ Bt[N,K]^T + bias)
// BM x 128 tile (BM = 128 or 64), BK=64, single-buffered LDS, 4 waves
// (2x2 of BM/2 x 64), 16x16x32 MFMA. global_load_lds staging with T2 XOR
// swizzle via pre-swizzled GLOBAL source (LDS linear; read addr same XOR).
// T1 XCD-aware bijective block swizzle for L2 panel locality.
// epi: 2 = +bias+res, fp32 out | 3 = gelu, bf16 out | 4 = qkv-split bf16 out
template<int BM>
__global__ __launch_bounds__(256) void mfma_gemm(
    const __bf16* __restrict__ A, const __bf16* __restrict__ Bt,
    const float* __restrict__ bias, const float* __restrict__ res,
    void* __restrict__ outv, int M, int N, int K, int epi, float scale)
{
    constexpr int MI = BM / 32;                 // M fragments per wave
    __shared__ __align__(16) __bf16 As[BM * 64];
    __shared__ __align__(16) __bf16 Bs[128 * 64];
    int tid = threadIdx.x;

    // T1: XCD-aware bijective block swizzle.
    int nwg = gridDim.x * gridDim.y;
    int orig = blockIdx.y * gridDim.x + blockIdx.x;
    int qq = nwg >> 3, rr = nwg & 7;
    int xcd = orig & 7, off = orig >> 3;
    int swz = (xcd < rr ? xcd * (qq + 1) : rr * (qq + 1) + (xcd - rr) * qq) + off;
    int tileM = (swz / gridDim.x) * BM;
    int tileN = (swz % gridDim.x) * 128;

    int wave = tid >> 6, lane = tid & 63;
    int wm = (wave >> 1) * (BM / 2), wn = (wave & 1) * 64;
    int lr = lane & 15, quad = lane >> 4;

    // Staging map (per round): idx = r*256+tid; LDS 16B-slot = idx (linear).
    // row = idx>>3, slot c' = idx&7; source chunk c = c'^(row&7).
    int srow = tid >> 3;                    // +32 per round
    int sc   = (tid & 7) ^ (srow & 7);      // round-invariant (32%8==0)
    const __bf16* Ap = A  + (size_t)(tileM + srow) * K + sc * 8;
    const __bf16* Bp = Bt + (size_t)(tileN + srow) * K + sc * 8;

    f32x4 acc[MI][4] = {};
    int rsw = lr & 7;                       // (row & 7) for fragment rows
    int nsteps = K >> 6;

    for (int t = 0; t < nsteps; t++) {
        __syncthreads();                    // previous tile's reads done
        #pragma unroll
        for (int r = 0; r < MI; r++)        // A: BM rows in MI rounds
            GLL16(Ap + t * 64 + (size_t)(r * 32) * K, As + (r * 256 + tid) * 8);
        #pragma unroll
        for (int r = 0; r < 4; r++)         // B: 128 rows in 4 rounds
            GLL16(Bp + t * 64 + (size_t)(r * 32) * K, Bs + (r * 256 + tid) * 8);
        __syncthreads();                    // drains vmcnt(0): tile visible
        #pragma unroll
        for (int ks = 0; ks < 2; ks++) {
            int ca = ((ks * 4 + quad) ^ rsw) * 8;   // swizzled chunk
            bf16x8 af[MI], bfr[4];
            #pragma unroll
            for (int i = 0; i < MI; i++)
                af[i]  = *(const bf16x8*)&As[(wm + i * 16 + lr) * 64 + ca];
            #pragma unroll
            for (int i = 0; i < 4; i++)
                bfr[i] = *(const bf16x8*)&Bs[(wn + i * 16 + lr) * 64 + ca];
            #pragma unroll
            for (int mi = 0; mi < MI; mi++)
                #pragma unroll
                for (int ni = 0; ni < 4; ni++)
                    acc[mi][ni] = __builtin_amdgcn_mfma_f32_16x16x32_bf16(
                        af[mi], bfr[ni], acc[mi][ni], 0, 0, 0);
        }
    }

    int zq = (epi == 4) ? tileN / HH : 0;
    #pragma unroll
    for (int mi = 0; mi < MI; mi++) {
        #pragma unroll
        for (int reg = 0; reg < 4; reg++) {
            int row = tileM + wm + mi * 16 + quad * 4 + reg;
            #pragma unroll
            for (int ni = 0; ni < 4; ni++) {
                int col = tileN + wn + ni * 16 + lr;
                float v = acc[mi][ni][reg] + bias[col];
                if (epi == 2) {
                    v += res[(size_t)row * N + col];
                    ((float*)outv)[(size_t)row * N + col] = v;
                } else if (epi == 3) {
                    float t = 0.7978845608028654f * (v + 0.044715f * v * v * v);
                    float e = __expf(2.f * t);
                    v = 0.5f * v * (2.f - 2.f / (e + 1.f));
                    ((__bf16*)outv)[(size_t)row * N + col] = (__bf16)v;
                } else {
                    // epi 4: qkv split, bf16 (q gets scale)
                    if (zq == 0) v *= scale;
                    size_t idx = ((size_t)zq * M + row) * HH + (col - zq * HH);
                    ((__bf16*)outv)[idx] = (__bf16)v;
                }
            }
        }
    }
}

// ---------------------------------------------------------------------------
// LayerNorm over H per row; in = pre-LN fp32 (bias+residual already fused in
// GEMM epilogue), writes fp32 + bf16.
__global__ __launch_bounds__(256) void ln_kernel(const float* __restrict__ in,
    const float* __restrict__ g, const float* __restrict__ b,
    float* __restrict__ out, __bf16* __restrict__ outb)
{
    int row = blockIdx.x;
    __shared__ float red[256];
    const float* x = in + (size_t)row * HH;
    int tid = threadIdx.x;
    float v[3];
    #pragma unroll
    for (int j = 0; j < 3; j++) v[j] = x[tid + j * 256];
    float s = v[0] + v[1] + v[2];
    red[tid] = s; __syncthreads();
    for (int st = 128; st > 0; st >>= 1) { if (tid < st) red[tid] += red[tid + st]; __syncthreads(); }
    float mean = red[0] / HH;
    __syncthreads();
    float vs = 0.f;
    #pragma unroll
    for (int j = 0; j < 3; j++) { float d = v[j] - mean; vs += d * d; }
    red[tid] = vs; __syncthreads();
    for (int st = 128; st > 0; st >>= 1) { if (tid < st) red[tid] += red[tid + st]; __syncthreads(); }
    float rstd = rsqrtf(red[0] / HH + 1e-5f);
    #pragma unroll
    for (int j = 0; j < 3; j++) {
        int i = tid + j * 256;
        float o = (v[j] - mean) * rstd * g[i] + b[i];
        out[(size_t)row * HH + i] = o;
        outb[(size_t)row * HH + i] = (__bf16)o;
    }
}

// ---------------------------------------------------------------------------
// Fused attention: band (flash, MFMA) + global-query pass1 in one launch.
// Grid (NHH, NQB + NCH, BB), 512 threads.
//  blockIdx.y <  NQB : band path, 128-query block, 8 waves x 16 queries.
//  blockIdx.y >= NQB : global-query pass1 chunk ch = blockIdx.y - NQB.
// Shared-LDS union (band 55.3 KB / pass1 43.7 KB).
#define GP_STRIDE (GG * DD + 2 * GG)
__global__ __launch_bounds__(512) void attn_fused(const __bf16* __restrict__ q,
    const __bf16* __restrict__ kg, const __bf16* __restrict__ vg,
    __bf16* __restrict__ ob, float* __restrict__ part)
{
    __shared__ __align__(16) char smem[55296];
    const int h  = blockIdx.x;
    const int b  = blockIdx.z;
    const int tid = threadIdx.x;

    if (blockIdx.y < NQB) {
        // =================== band path ===================
        typedef __bf16 row72[72];
        row72* Qs = (row72*)(smem);             // [128][72]
        row72* Ks = (row72*)(smem + 18432);     // [64][72]
        row72* Vt = (row72*)(smem + 27648);     // [64][72]  Vt[d][key]
        row72* Pw = (row72*)(smem + 36864);     // [128][72]

        const int c0 = blockIdx.y * 128;
        const int wave = tid >> 6, lane = tid & 63;
        const int lr = lane & 15, quad = lane >> 4;

        {   // stage Q rows c0..c0+127
            int r = tid >> 2, dq = (tid & 3) * 16;
            const __bf16* qp = q + (((size_t)b * SS + c0 + r) * NHH + h) * DD + dq;
            *(bf16x8*)&Qs[r][dq]     = *(const bf16x8*)qp;
            *(bf16x8*)&Qs[r][dq + 8] = *(const bf16x8*)(qp + 8);
        }
        __syncthreads();
        bf16x8 aq0 = *(const bf16x8*)&Qs[wave * 16 + lr][quad * 8];
        bf16x8 aq1 = *(const bf16x8*)&Qs[wave * 16 + lr][32 + quad * 8];

        f32x4 O[4] = {};
        f32x4 m_run = {-1e30f, -1e30f, -1e30f, -1e30f};
        f32x4 l_run = {0.f, 0.f, 0.f, 0.f};

        int lo = c0 - WW; if (lo < GG) lo = GG;
        int hi = c0 + 127 + WW; if (hi > SS - 1) hi = SS - 1;
        int nband = (hi - lo + 64) / 64;
        const int qw0 = c0 + wave * 16;
        const int q0 = qw0 + quad * 4;

        for (int t = 0; t <= nband; t++) {
            int kbase = (t == 0) ? 0 : lo + (t - 1) * 64;
            int kend  = (t == 0) ? GG : (kbase + 64 < hi + 1 ? kbase + 64 : hi + 1);

            __syncthreads();
            {   // K rows: 512 threads, one bf16x8 each
                int r = tid >> 3, dq = (tid & 7) * 8;
                int kpos = kbase + r;
                if (kpos < kend) {
                    const __bf16* kp = kg + (((size_t)b * SS + kpos) * NHH + h) * DD + dq;
                    *(bf16x8*)&Ks[r][dq] = *(const bf16x8*)kp;
                }
            }
            {   // V transposed: group (tid>>6) stages dims [8g, 8g+8)
                int r2 = tid & 63, dg = (tid >> 6) * 8;
                int kpos = kbase + r2;
                if (kpos < kend) {
                    const __bf16* vp = vg + (((size_t)b * SS + kpos) * NHH + h) * DD + dg;
                    bf16x8 f0 = *(const bf16x8*)vp;
                    #pragma unroll
                    for (int u = 0; u < 8; u++) Vt[dg + u][r2] = f0[u];
                } else {
                    #pragma unroll
                    for (int u = 0; u < 8; u++) Vt[dg + u][r2] = (__bf16)0.f;
                }
            }
            __syncthreads();

            // wave-level skip: tile entirely outside this wave's window
            if (t > 0 && (kbase > qw0 + 15 + WW || kbase + 63 < qw0 - WW))
                continue;

            f32x4 S[4] = {};
            #pragma unroll
            for (int nt = 0; nt < 4; nt++) {
                bf16x8 k0v = *(const bf16x8*)&Ks[nt * 16 + lr][quad * 8];
                bf16x8 k1v = *(const bf16x8*)&Ks[nt * 16 + lr][32 + quad * 8];
                S[nt] = __builtin_amdgcn_mfma_f32_16x16x32_bf16(aq0, k0v, S[nt], 0, 0, 0);
                S[nt] = __builtin_amdgcn_mfma_f32_16x16x32_bf16(aq1, k1v, S[nt], 0, 0, 0);
            }
            bool glob = (t == 0);
            #pragma unroll
            for (int nt = 0; nt < 4; nt++) {
                int key = kbase + nt * 16 + lr;
                #pragma unroll
                for (int r = 0; r < 4; r++) {
                    int dd = key - (q0 + r);
                    bool ok = (key < kend) && (glob || (dd <= WW && dd >= -WW));
                    if (!ok) S[nt][r] = -1e9f;
                }
            }
            float al[4];
            #pragma unroll
            for (int r = 0; r < 4; r++) {
                float m = fmaxf(fmaxf(S[0][r], S[1][r]), fmaxf(S[2][r], S[3][r]));
                m = fmaxf(m, __shfl_xor(m, 1));
                m = fmaxf(m, __shfl_xor(m, 2));
                m = fmaxf(m, __shfl_xor(m, 4));
                m = fmaxf(m, __shfl_xor(m, 8));
                float mo = m_run[r];
                float mn = fmaxf(mo, m);
                m_run[r] = mn;
                al[r] = __expf(mo - mn);
            }
            #pragma unroll
            for (int nt = 0; nt < 4; nt++)
                #pragma unroll
                for (int r = 0; r < 4; r++)
                    S[nt][r] = __expf(S[nt][r] - m_run[r]);
            #pragma unroll
            for (int r = 0; r < 4; r++) {
                float s = S[0][r] + S[1][r] + S[2][r] + S[3][r];
                s += __shfl_xor(s, 1);
                s += __shfl_xor(s, 2);
                s += __shfl_xor(s, 4);
                s += __shfl_xor(s, 8);
                l_run[r] = l_run[r] * al[r] + s;
                O[0][r] *= al[r]; O[1][r] *= al[r]; O[2][r] *= al[r]; O[3][r] *= al[r];
            }
            #pragma unroll
            for (int nt = 0; nt < 4; nt++)
                #pragma unroll
                for (int r = 0; r < 4; r++)
                    Pw[wave * 16 + quad * 4 + r][nt * 16 + lr] = (__bf16)S[nt][r];
            asm volatile("s_waitcnt lgkmcnt(0)" ::: "memory");  // intra-wave
            bf16x8 pa0 = *(const bf16x8*)&Pw[wave * 16 + lr][quad * 8];
            bf16x8 pa1 = *(const bf16x8*)&Pw[wave * 16 + lr][32 + quad * 8];
            #pragma unroll
            for (int nt = 0; nt < 4; nt++) {
                bf16x8 v0v = *(const bf16x8*)&Vt[nt * 16 + lr][quad * 8];
                bf16x8 v1v = *(const bf16x8*)&Vt[nt * 16 + lr][32 + quad * 8];
                O[nt] = __builtin_amdgcn_mfma_f32_16x16x32_bf16(pa0, v0v, O[nt], 0, 0, 0);
                O[nt] = __builtin_amdgcn_mfma_f32_16x16x32_bf16(pa1, v1v, O[nt], 0, 0, 0);
            }
        }

        #pragma unroll
        for (int r = 0; r < 4; r++) {
            int qg = q0 + r;
            float invl = 1.f / l_run[r];
            #pragma unroll
            for (int nt = 0; nt < 4; nt++) {
                int d = nt * 16 + lr;
                ob[(((size_t)b * SS + qg) * NHH + h) * DD + d] = (__bf16)(O[nt][r] * invl);
            }
        }
    } else {
        // =================== global-query pass1 path ===================
        typedef float frow68[68];
        frow68* Qs  = (frow68*)(smem);              // [16][68]
        frow68* Kt  = (frow68*)(smem + 4352);       // [64][68] Kt[d][key]
        frow68* Vs  = (frow68*)(smem + 21760);      // [64][68] Vs[key][d]
        typedef float frow17[17];
        frow17* Ssc = (frow17*)(smem + 39168);      // [64][17]
        float* m_sh  = (float*)(smem + 43520);
        float* l_sh  = m_sh + GG;
        float* al_sh = l_sh + GG;

        const int ch = blockIdx.y - NQB;
        int q_i = tid >> 5;   // query 0..15
        int g_i = tid & 31;   // group 0..31

        {   // load 16 global Q rows (2 bf16 -> f32 per thread)
            const __bf16* qp = q + (((size_t)b * SS + q_i) * NHH + h) * DD + g_i * 2;
            Qs[q_i][g_i * 2]     = (float)qp[0];
            Qs[q_i][g_i * 2 + 1] = (float)qp[1];
        }
        if (tid < GG) { m_sh[tid] = -1e30f; l_sh[tid] = 0.f; }

        float O0 = 0.f, O1 = 0.f;

        for (int t = 0; t < 4; t++) {
            int kbase = ch * 256 + t * 64;
            __syncthreads();
            {   // stage K/V tile: r = key 0..63, dq = 8-dim chunk
                int r = tid >> 3, dq = (tid & 7) * 8;
                const __bf16* kp = kg + (((size_t)b * SS + kbase + r) * NHH + h) * DD + dq;
                const __bf16* vp = vg + (((size_t)b * SS + kbase + r) * NHH + h) * DD + dq;
                bf16x8 k0 = *(const bf16x8*)kp;
                bf16x8 v0 = *(const bf16x8*)vp;
                #pragma unroll
                for (int u = 0; u < 8; u++) {
                    Kt[dq + u][r] = (float)k0[u];
                    Vs[r][dq + u] = (float)v0[u];
                }
            }
            __syncthreads();

            // scores: thread (q_i, g_i) -> keys g_i*2, g_i*2+1
            float s0 = 0.f, s1 = 0.f;
            for (int d = 0; d < 64; d++) {
                float qv = Qs[q_i][d];
                s0 += qv * Kt[d][g_i * 2];
                s1 += qv * Kt[d][g_i * 2 + 1];
            }
            Ssc[g_i * 2][q_i]     = s0;
            Ssc[g_i * 2 + 1][q_i] = s1;
            __syncthreads();

            if (tid < GG) {
                float mo = m_sh[tid], mx = mo;
                for (int kk = 0; kk < 64; kk++) mx = fmaxf(mx, Ssc[kk][tid]);
                float al = __expf(mo - mx);
                al_sh[tid] = al; m_sh[tid] = mx;
                float s = 0.f;
                for (int kk = 0; kk < 64; kk++) {
                    float p = __expf(Ssc[kk][tid] - mx);
                    Ssc[kk][tid] = p;
                    s += p;
                }
                l_sh[tid] = l_sh[tid] * al + s;
            }
            __syncthreads();

            // PV: thread (q_i, g_i) accumulates dims g_i*2, g_i*2+1
            float al = al_sh[q_i];
            O0 *= al; O1 *= al;
            for (int kk = 0; kk < 64; kk++) {
                float p = Ssc[kk][q_i];
                O0 += p * Vs[kk][g_i * 2];
                O1 += p * Vs[kk][g_i * 2 + 1];
            }
        }
        __syncthreads();

        size_t base = (((size_t)b * NHH + h) * NCH + ch) * GP_STRIDE;
        part[base + q_i * DD + g_i * 2]     = O0;
        part[base + q_i * DD + g_i * 2 + 1] = O1;
        if (tid < GG) {
            part[base + GG * DD + tid] = m_sh[tid];
            part[base + GG * DD + GG + tid] = l_sh[tid];
        }
    }
}

// ---------------------------------------------------------------------------
// Global-query attention pass 2: merge NCH chunk partials, write bf16 rows.
__global__ __launch_bounds__(64) void global_attn_combine(const float* __restrict__ part,
    __bf16* __restrict__ ob)
{
    int g = blockIdx.x, h = blockIdx.y, b = blockIdx.z;
    int d = threadIdx.x;
    size_t base0 = (((size_t)b * NHH + h) * NCH) * GP_STRIDE;
    float m[NCH], l[NCH], M = -1e30f;
    #pragma unroll
    for (int ch = 0; ch < NCH; ch++) {
        m[ch] = part[base0 + ch * GP_STRIDE + GG * DD + g];
        l[ch] = part[base0 + ch * GP_STRIDE + GG * DD + GG + g];
        M = fmaxf(M, m[ch]);
    }
    float L = 0.f, o = 0.f;
    #pragma unroll
    for (int ch = 0; ch < NCH; ch++) {
        float w = __expf(m[ch] - M);
        L += w * l[ch];
        o += w * part[base0 + ch * GP_STRIDE + g * DD + d];
    }
    ob[(((size_t)b * SS + g) * NHH + h) * DD + d] = (__bf16)(o / L);
}

// ---------------------------------------------------------------------------
// Pair head: out[row,:] = concat(x[b,i,:], x[b,j,:]) @ Wh + bh
__global__ __launch_bounds__(256) void pair_head_kernel(const float* __restrict__ x,
    const int* __restrict__ pairs, const float* __restrict__ Wh,
    const float* __restrict__ bh, float* __restrict__ out)
{
    int row = blockIdx.x;
    int b = row / PP;
    int i = pairs[row * 2 + 0];
    int j = pairs[row * 2 + 1];
    const float* xi = x + ((size_t)b * SS + i) * HH;
    const float* xj = x + ((size_t)b * SS + j) * HH;
    float acc[NLL] = {};
    for (int e = threadIdx.x; e < 2 * HH; e += 256) {
        float val = (e < HH) ? xi[e] : xj[e - HH];
        #pragma unroll
        for (int c = 0; c < NLL; c++) acc[c] += val * Wh[e * NLL + c];
    }
    __shared__ float red[NLL * 256];
    #pragma unroll
    for (int c = 0; c < NLL; c++) red[c * 256 + threadIdx.x] = acc[c];
    __syncthreads();
    for (int st = 128; st > 0; st >>= 1) {
        if (threadIdx.x < st)
            #pragma unroll
            for (int c = 0; c < NLL; c++)
                red[c * 256 + threadIdx.x] += red[c * 256 + threadIdx.x + st];
        __syncthreads();
    }
    if (threadIdx.x < NLL) out[row * NLL + threadIdx.x] = red[threadIdx.x * 256] + bh[threadIdx.x];
}

// ---------------------------------------------------------------------------
extern "C" void kernel_launch(void* const* d_in, const int* in_sizes, int n_in,
                              void* d_out, int out_size, void* d_ws, size_t ws_size,
                              hipStream_t stream)
{
    const int*   input_ids    = (const int*)d_in[0];
    const int*   pair_indices = (const int*)d_in[1];
    const float* emb   = (const float*)d_in[2];
    const float* Wq    = (const float*)d_in[3];
    const float* bq    = (const float*)d_in[4];
    const float* Wk    = (const float*)d_in[5];
    const float* bk    = (const float*)d_in[6];
    const float* Wv    = (const float*)d_in[7];
    const float* bv    = (const float*)d_in[8];
    const float* Wo    = (const float*)d_in[9];
    const float* bo    = (const float*)d_in[10];
    const float* ln1_g = (const float*)d_in[11];
    const float* ln1_b = (const float*)d_in[12];
    const float* Wf1   = (const float*)d_in[13];
    const float* bf1   = (const float*)d_in[14];
    const float* Wf2   = (const float*)d_in[15];
    const float* bf2   = (const float*)d_in[16];
    const float* ln2_g = (const float*)d_in[17];
    const float* ln2_b = (const float*)d_in[18];
    const float* Wh    = (const float*)d_in[19];
    const float* bh    = (const float*)d_in[20];

    const size_t R = (size_t)BB * SS;
    const size_t LWS = 4 * (size_t)HH * HH + 2 * (size_t)HH * FF;

    char* w = (char*)d_ws;
    float* x      = (float*)w;  w += R * HH * 4;
    float* t1     = (float*)w;  w += R * HH * 4;
    __bf16* qkv_bf = (__bf16*)w; w += 3 * R * HH * 2;
    __bf16* x_bf  = (__bf16*)w; w += R * HH * 2;
    __bf16* o_bf  = (__bf16*)w; w += R * HH * 2;
    __bf16* hb_bf = (__bf16*)w; w += R * FF * 2;
    float* bias_qkv = (float*)w; w += LL * 3 * HH * 4;
    float* gpart  = (float*)w;  w += (size_t)BB * NHH * NCH * GP_STRIDE * 4;
    __bf16* Wbf   = (__bf16*)w; w += LL * LWS * 2;
    __bf16* qb = qkv_bf;
    __bf16* kb = qkv_bf + R * HH;
    __bf16* vb = qkv_bf + 2 * R * HH;

    pack_bias_kernel<<<dim3(LL), 256, 0, stream>>>(bq, bk, bv, bias_qkv);
    size_t hh = (size_t)HH * HH, hf = (size_t)HH * FF;
    transpose_bf16_kernel<<<dim3(HH/32, HH/32, LL), 256, 0, stream>>>(Wq, Wbf,            HH, HH, hh, LWS);
    transpose_bf16_kernel<<<dim3(HH/32, HH/32, LL), 256, 0, stream>>>(Wk, Wbf + hh,       HH, HH, hh, LWS);
    transpose_bf16_kernel<<<dim3(HH/32, HH/32, LL), 256, 0, stream>>>(Wv, Wbf + 2 * hh,   HH, HH, hh, LWS);
    transpose_bf16_kernel<<<dim3(HH/32, HH/32, LL), 256, 0, stream>>>(Wo, Wbf + 3 * hh,   HH, HH, hh, LWS);
    transpose_bf16_kernel<<<dim3(FF/32, HH/32, LL), 256, 0, stream>>>(Wf1, Wbf + 4 * hh,  HH, FF, hf, LWS);
    transpose_bf16_kernel<<<dim3(HH/32, FF/32, LL), 256, 0, stream>>>(Wf2, Wbf + 4 * hh + hf, FF, HH, hf, LWS);

    embed_kernel<<<dim3((int)R), 256, 0, stream>>>(input_ids, emb, x, x_bf);

    for (int l = 0; l < LL; l++) {
        __bf16* Wl = Wbf + (size_t)l * LWS;
        const float* lbo  = bo  + (size_t)l * HH;
        const float* lg1  = ln1_g + (size_t)l * HH;  const float* lb1 = ln1_b + (size_t)l * HH;
        const float* lbf1 = bf1 + (size_t)l * FF;
        const float* lbf2 = bf2 + (size_t)l * HH;
        const float* lg2  = ln2_g + (size_t)l * HH;  const float* lb2 = ln2_b + (size_t)l * HH;

        // QKV: bf16 outputs (q pre-scaled)
        mfma_gemm<128><<<dim3(3 * HH / 128, R / 128), 256, 0, stream>>>(
            x_bf, Wl, bias_qkv + (size_t)l * 3 * HH, nullptr, qkv_bf,
            (int)R, 3 * HH, HH, 4, 0.125f);

        // band + global pass1 fused; combine merges chunk partials
        attn_fused<<<dim3(NHH, NQB + NCH, BB), 512, 0, stream>>>(qb, kb, vb, o_bf, gpart);
        global_attn_combine<<<dim3(GG, NHH, BB), 64, 0, stream>>>(gpart, o_bf);

        // attn-out: 64x128 tiles, fused bias+residual -> t1 (fp32)
        mfma_gemm<64><<<dim3(HH / 128, R / 64), 256, 0, stream>>>(
            o_bf, Wl + 3 * hh, lbo, x, t1, (int)R, HH, HH, 2, 0.f);
        ln_kernel<<<dim3((int)R), 256, 0, stream>>>(t1, lg1, lb1, x, x_bf);

        mfma_gemm<128><<<dim3(FF / 128, R / 128), 256, 0, stream>>>(
            x_bf, Wl + 4 * hh, lbf1, nullptr, hb_bf, (int)R, FF, HH, 3, 0.f);

        // FF2: 64x128 tiles, fused bias+residual -> t1 (fp32)
        mfma_gemm<64><<<dim3(HH / 128, R / 64), 256, 0, stream>>>(
            hb_bf, Wl + 4 * hh + hf, lbf2, x, t1, (int)R, HH, FF, 2, 0.f);
        ln_kernel<<<dim3((int)R), 256, 0, stream>>>(t1, lg2, lb2, x, x_bf);
    }

    pair_head_kernel<<<dim3(BB * PP), 256, 0, stream>>>(x, pair_indices, Wh, bh, (float*)d_out);
}

// Round 6
// 1162.913 us; speedup vs baseline: 1.1970x; 1.0378x over previous
//
#include <hip/hip_runtime.h>
#include <math.h>

#define BB 2
#define SS 2048
#define HH 768
#define NHH 12
#define LL 4
#define DD 64
#define WW 128
#define GG 16
#define PP 128
#define NLL 3
#define FF 3072
#define NCH 8    // key chunks for global-attention flash-decoding split
#define NQB 16   // band query blocks per (h,b) = SS/128

typedef __bf16 bf16x8 __attribute__((ext_vector_type(8)));
typedef __bf16 bf16x4 __attribute__((ext_vector_type(4)));
typedef float f32x4 __attribute__((ext_vector_type(4)));

// Async global->LDS direct load, 16B per lane. LDS dest must be
// wave-uniform base + lane*16 (linear layout).
#define GLL16(gp, lp) __builtin_amdgcn_global_load_lds( \
    (__attribute__((address_space(1))) void*)(gp),      \
    (__attribute__((address_space(3))) void*)(lp), 16, 0, 0)

// ---------------------------------------------------------------------------
// Embedding gather: x[row,:] = emb[ids[row],:], plus bf16 copy.
__global__ __launch_bounds__(256) void embed_kernel(const int* __restrict__ ids,
    const float* __restrict__ emb, float* __restrict__ x, __bf16* __restrict__ xb)
{
    int row = blockIdx.x;
    int id = ids[row];
    const float* e = emb + (size_t)id * HH;
    float* xp = x + (size_t)row * HH;
    __bf16* xbp = xb + (size_t)row * HH;
    for (int i = threadIdx.x; i < HH; i += 256) {
        float v = e[i];
        xp[i] = v;
        xbp[i] = (__bf16)v;
    }
}

// ---------------------------------------------------------------------------
// Pack per-layer q,k,v biases into [L][3*H]
__global__ __launch_bounds__(256) void pack_bias_kernel(const float* __restrict__ bq,
    const float* __restrict__ bk, const float* __restrict__ bv, float* __restrict__ dst)
{
    int l = blockIdx.x;
    for (int i = threadIdx.x; i < HH; i += 256) {
        dst[(size_t)l * 3 * HH + i]          = bq[(size_t)l * HH + i];
        dst[(size_t)l * 3 * HH + HH + i]     = bk[(size_t)l * HH + i];
        dst[(size_t)l * 3 * HH + 2 * HH + i] = bv[(size_t)l * HH + i];
    }
}

// ---------------------------------------------------------------------------
// Transpose + fp32->bf16: src [K][N] fp32 -> dst [N][K] bf16. blockIdx.z = layer.
__global__ __launch_bounds__(256) void transpose_bf16_kernel(const float* __restrict__ src,
    __bf16* __restrict__ dst, int K, int N, size_t src_ls, size_t dst_ls)
{
    int l = blockIdx.z;
    src += (size_t)l * src_ls;
    dst += (size_t)l * dst_ls;
    __shared__ float t[32][33];
    int tx = threadIdx.x & 31, ty = threadIdx.x >> 5;  // 32 x 8
    int n0 = blockIdx.x * 32, k0 = blockIdx.y * 32;
    for (int i = ty; i < 32; i += 8)
        t[i][tx] = src[(size_t)(k0 + i) * N + n0 + tx];
    __syncthreads();
    for (int i = ty; i < 32; i += 8)
        dst[(size_t)(n0 + i) * K + k0 + tx] = (__bf16)t[tx][i];
}

// ---------------------------------------------------------------------------
// bf16 MFMA GEMM: C[M,N] = epi(A[M,K] @ Bt[N,K]^T + bias)
// BM x BN tile (BM,BN in {64,128}), BK=64, single-buffered LDS, 4 waves
// (2x2 of BM/2 x BN/2), 16x16x32 MFMA. global_load_lds staging with T2 XOR
// swizzle via pre-swizzled GLOBAL source (LDS linear; read addr same XOR).
// T1 XCD-aware bijective block swizzle for L2 panel locality.
// Small tiles raise blocks/CU for the short-K grid-starved shapes.
// epi: 2 = +bias+res, fp32 out | 3 = gelu, bf16 out | 4 = qkv-split bf16 out
template<int BM, int BN>
__global__ __launch_bounds__(256) void mfma_gemm(
    const __bf16* __restrict__ A, const __bf16* __restrict__ Bt,
    const float* __restrict__ bias, const float* __restrict__ res,
    void* __restrict__ outv, int M, int N, int K, int epi, float scale)
{
    constexpr int WMI = BM / 32;                // M fragments per wave
    constexpr int WNI = BN / 32;                // N fragments per wave
    __shared__ __align__(16) __bf16 As[BM * 64];
    __shared__ __align__(16) __bf16 Bs[BN * 64];
    int tid = threadIdx.x;

    // T1: XCD-aware bijective block swizzle.
    int nwg = gridDim.x * gridDim.y;
    int orig = blockIdx.y * gridDim.x + blockIdx.x;
    int qq = nwg >> 3, rr = nwg & 7;
    int xcd = orig & 7, off = orig >> 3;
    int swz = (xcd < rr ? xcd * (qq + 1) : rr * (qq + 1) + (xcd - rr) * qq) + off;
    int tileM = (swz / gridDim.x) * BM;
    int tileN = (swz % gridDim.x) * BN;

    int wave = tid >> 6, lane = tid & 63;
    int wm = (wave >> 1) * (BM / 2), wn = (wave & 1) * (BN / 2);
    int lr = lane & 15, quad = lane >> 4;

    // Staging map (per round): idx = r*256+tid; LDS 16B-slot = idx (linear).
    // row = idx>>3, slot c' = idx&7; source chunk c = c'^(row&7).
    int srow = tid >> 3;                    // +32 per round
    int sc   = (tid & 7) ^ (srow & 7);      // round-invariant (32%8==0)
    const __bf16* Ap = A  + (size_t)(tileM + srow) * K + sc * 8;
    const __bf16* Bp = Bt + (size_t)(tileN + srow) * K + sc * 8;

    f32x4 acc[WMI][WNI] = {};
    int rsw = lr & 7;                       // (row & 7) for fragment rows
    int nsteps = K >> 6;

    for (int t = 0; t < nsteps; t++) {
        __syncthreads();                    // previous tile's reads done
        #pragma unroll
        for (int r = 0; r < WMI; r++)       // A: BM rows in WMI rounds
            GLL16(Ap + t * 64 + (size_t)(r * 32) * K, As + (r * 256 + tid) * 8);
        #pragma unroll
        for (int r = 0; r < WNI; r++)       // B: BN rows in WNI rounds
            GLL16(Bp + t * 64 + (size_t)(r * 32) * K, Bs + (r * 256 + tid) * 8);
        __syncthreads();                    // drains vmcnt(0): tile visible
        #pragma unroll
        for (int ks = 0; ks < 2; ks++) {
            int ca = ((ks * 4 + quad) ^ rsw) * 8;   // swizzled chunk
            bf16x8 af[WMI], bfr[WNI];
            #pragma unroll
            for (int i = 0; i < WMI; i++)
                af[i]  = *(const bf16x8*)&As[(wm + i * 16 + lr) * 64 + ca];
            #pragma unroll
            for (int i = 0; i < WNI; i++)
                bfr[i] = *(const bf16x8*)&Bs[(wn + i * 16 + lr) * 64 + ca];
            #pragma unroll
            for (int mi = 0; mi < WMI; mi++)
                #pragma unroll
                for (int ni = 0; ni < WNI; ni++)
                    acc[mi][ni] = __builtin_amdgcn_mfma_f32_16x16x32_bf16(
                        af[mi], bfr[ni], acc[mi][ni], 0, 0, 0);
        }
    }

    int zq = (epi == 4) ? tileN / HH : 0;
    #pragma unroll
    for (int mi = 0; mi < WMI; mi++) {
        #pragma unroll
        for (int reg = 0; reg < 4; reg++) {
            int row = tileM + wm + mi * 16 + quad * 4 + reg;
            #pragma unroll
            for (int ni = 0; ni < WNI; ni++) {
                int col = tileN + wn + ni * 16 + lr;
                float v = acc[mi][ni][reg] + bias[col];
                if (epi == 2) {
                    v += res[(size_t)row * N + col];
                    ((float*)outv)[(size_t)row * N + col] = v;
                } else if (epi == 3) {
                    float t = 0.7978845608028654f * (v + 0.044715f * v * v * v);
                    float e = __expf(2.f * t);
                    v = 0.5f * v * (2.f - 2.f / (e + 1.f));
                    ((__bf16*)outv)[(size_t)row * N + col] = (__bf16)v;
                } else {
                    // epi 4: qkv split, bf16 (q gets scale)
                    if (zq == 0) v *= scale;
                    size_t idx = ((size_t)zq * M + row) * HH + (col - zq * HH);
                    ((__bf16*)outv)[idx] = (__bf16)v;
                }
            }
        }
    }
}

// ---------------------------------------------------------------------------
// LayerNorm over H per row; in = pre-LN fp32 (bias+residual already fused in
// GEMM epilogue), writes fp32 + bf16.
__global__ __launch_bounds__(256) void ln_kernel(const float* __restrict__ in,
    const float* __restrict__ g, const float* __restrict__ b,
    float* __restrict__ out, __bf16* __restrict__ outb)
{
    int row = blockIdx.x;
    __shared__ float red[256];
    const float* x = in + (size_t)row * HH;
    int tid = threadIdx.x;
    float v[3];
    #pragma unroll
    for (int j = 0; j < 3; j++) v[j] = x[tid + j * 256];
    float s = v[0] + v[1] + v[2];
    red[tid] = s; __syncthreads();
    for (int st = 128; st > 0; st >>= 1) { if (tid < st) red[tid] += red[tid + st]; __syncthreads(); }
    float mean = red[0] / HH;
    __syncthreads();
    float vs = 0.f;
    #pragma unroll
    for (int j = 0; j < 3; j++) { float d = v[j] - mean; vs += d * d; }
    red[tid] = vs; __syncthreads();
    for (int st = 128; st > 0; st >>= 1) { if (tid < st) red[tid] += red[tid + st]; __syncthreads(); }
    float rstd = rsqrtf(red[0] / HH + 1e-5f);
    #pragma unroll
    for (int j = 0; j < 3; j++) {
        int i = tid + j * 256;
        float o = (v[j] - mean) * rstd * g[i] + b[i];
        out[(size_t)row * HH + i] = o;
        outb[(size_t)row * HH + i] = (__bf16)o;
    }
}

// ---------------------------------------------------------------------------
// Fused attention: band (flash, MFMA) + global-query pass1 in one launch.
// Grid (NHH, NQB + NCH, BB), 512 threads.
//  blockIdx.y <  NQB : band path, 128-query block, 8 waves x 16 queries.
//  blockIdx.y >= NQB : global-query pass1 chunk ch = blockIdx.y - NQB.
// Shared-LDS union (band 55.3 KB / pass1 43.7 KB).
#define GP_STRIDE (GG * DD + 2 * GG)
__global__ __launch_bounds__(512) void attn_fused(const __bf16* __restrict__ q,
    const __bf16* __restrict__ kg, const __bf16* __restrict__ vg,
    __bf16* __restrict__ ob, float* __restrict__ part)
{
    __shared__ __align__(16) char smem[55296];
    const int h  = blockIdx.x;
    const int b  = blockIdx.z;
    const int tid = threadIdx.x;

    if (blockIdx.y < NQB) {
        // =================== band path ===================
        typedef __bf16 row72[72];
        row72* Qs = (row72*)(smem);             // [128][72]
        row72* Ks = (row72*)(smem + 18432);     // [64][72]
        row72* Vt = (row72*)(smem + 27648);     // [64][72]  Vt[d][key]
        row72* Pw = (row72*)(smem + 36864);     // [128][72]

        const int c0 = blockIdx.y * 128;
        const int wave = tid >> 6, lane = tid & 63;
        const int lr = lane & 15, quad = lane >> 4;

        {   // stage Q rows c0..c0+127
            int r = tid >> 2, dq = (tid & 3) * 16;
            const __bf16* qp = q + (((size_t)b * SS + c0 + r) * NHH + h) * DD + dq;
            *(bf16x8*)&Qs[r][dq]     = *(const bf16x8*)qp;
            *(bf16x8*)&Qs[r][dq + 8] = *(const bf16x8*)(qp + 8);
        }
        __syncthreads();
        bf16x8 aq0 = *(const bf16x8*)&Qs[wave * 16 + lr][quad * 8];
        bf16x8 aq1 = *(const bf16x8*)&Qs[wave * 16 + lr][32 + quad * 8];

        f32x4 O[4] = {};
        f32x4 m_run = {-1e30f, -1e30f, -1e30f, -1e30f};
        f32x4 l_run = {0.f, 0.f, 0.f, 0.f};

        int lo = c0 - WW; if (lo < GG) lo = GG;
        int hi = c0 + 127 + WW; if (hi > SS - 1) hi = SS - 1;
        int nband = (hi - lo + 64) / 64;
        const int qw0 = c0 + wave * 16;
        const int q0 = qw0 + quad * 4;

        for (int t = 0; t <= nband; t++) {
            int kbase = (t == 0) ? 0 : lo + (t - 1) * 64;
            int kend  = (t == 0) ? GG : (kbase + 64 < hi + 1 ? kbase + 64 : hi + 1);

            __syncthreads();
            {   // K rows: 512 threads, one bf16x8 each
                int r = tid >> 3, dq = (tid & 7) * 8;
                int kpos = kbase + r;
                if (kpos < kend) {
                    const __bf16* kp = kg + (((size_t)b * SS + kpos) * NHH + h) * DD + dq;
                    *(bf16x8*)&Ks[r][dq] = *(const bf16x8*)kp;
                }
            }
            {   // V transposed: group (tid>>6) stages dims [8g, 8g+8)
                int r2 = tid & 63, dg = (tid >> 6) * 8;
                int kpos = kbase + r2;
                if (kpos < kend) {
                    const __bf16* vp = vg + (((size_t)b * SS + kpos) * NHH + h) * DD + dg;
                    bf16x8 f0 = *(const bf16x8*)vp;
                    #pragma unroll
                    for (int u = 0; u < 8; u++) Vt[dg + u][r2] = f0[u];
                } else {
                    #pragma unroll
                    for (int u = 0; u < 8; u++) Vt[dg + u][r2] = (__bf16)0.f;
                }
            }
            __syncthreads();

            // wave-level skip: tile entirely outside this wave's window
            if (t > 0 && (kbase > qw0 + 15 + WW || kbase + 63 < qw0 - WW))
                continue;

            f32x4 S[4] = {};
            #pragma unroll
            for (int nt = 0; nt < 4; nt++) {
                bf16x8 k0v = *(const bf16x8*)&Ks[nt * 16 + lr][quad * 8];
                bf16x8 k1v = *(const bf16x8*)&Ks[nt * 16 + lr][32 + quad * 8];
                S[nt] = __builtin_amdgcn_mfma_f32_16x16x32_bf16(aq0, k0v, S[nt], 0, 0, 0);
                S[nt] = __builtin_amdgcn_mfma_f32_16x16x32_bf16(aq1, k1v, S[nt], 0, 0, 0);
            }
            bool glob = (t == 0);
            #pragma unroll
            for (int nt = 0; nt < 4; nt++) {
                int key = kbase + nt * 16 + lr;
                #pragma unroll
                for (int r = 0; r < 4; r++) {
                    int dd = key - (q0 + r);
                    bool ok = (key < kend) && (glob || (dd <= WW && dd >= -WW));
                    if (!ok) S[nt][r] = -1e9f;
                }
            }
            float al[4];
            #pragma unroll
            for (int r = 0; r < 4; r++) {
                float m = fmaxf(fmaxf(S[0][r], S[1][r]), fmaxf(S[2][r], S[3][r]));
                m = fmaxf(m, __shfl_xor(m, 1));
                m = fmaxf(m, __shfl_xor(m, 2));
                m = fmaxf(m, __shfl_xor(m, 4));
                m = fmaxf(m, __shfl_xor(m, 8));
                float mo = m_run[r];
                float mn = fmaxf(mo, m);
                m_run[r] = mn;
                al[r] = __expf(mo - mn);
            }
            #pragma unroll
            for (int nt = 0; nt < 4; nt++)
                #pragma unroll
                for (int r = 0; r < 4; r++)
                    S[nt][r] = __expf(S[nt][r] - m_run[r]);
            #pragma unroll
            for (int r = 0; r < 4; r++) {
                float s = S[0][r] + S[1][r] + S[2][r] + S[3][r];
                s += __shfl_xor(s, 1);
                s += __shfl_xor(s, 2);
                s += __shfl_xor(s, 4);
                s += __shfl_xor(s, 8);
                l_run[r] = l_run[r] * al[r] + s;
                O[0][r] *= al[r]; O[1][r] *= al[r]; O[2][r] *= al[r]; O[3][r] *= al[r];
            }
            #pragma unroll
            for (int nt = 0; nt < 4; nt++)
                #pragma unroll
                for (int r = 0; r < 4; r++)
                    Pw[wave * 16 + quad * 4 + r][nt * 16 + lr] = (__bf16)S[nt][r];
            asm volatile("s_waitcnt lgkmcnt(0)" ::: "memory");  // intra-wave
            bf16x8 pa0 = *(const bf16x8*)&Pw[wave * 16 + lr][quad * 8];
            bf16x8 pa1 = *(const bf16x8*)&Pw[wave * 16 + lr][32 + quad * 8];
            #pragma unroll
            for (int nt = 0; nt < 4; nt++) {
                bf16x8 v0v = *(const bf16x8*)&Vt[nt * 16 + lr][quad * 8];
                bf16x8 v1v = *(const bf16x8*)&Vt[nt * 16 + lr][32 + quad * 8];
                O[nt] = __builtin_amdgcn_mfma_f32_16x16x32_bf16(pa0, v0v, O[nt], 0, 0, 0);
                O[nt] = __builtin_amdgcn_mfma_f32_16x16x32_bf16(pa1, v1v, O[nt], 0, 0, 0);
            }
        }

        #pragma unroll
        for (int r = 0; r < 4; r++) {
            int qg = q0 + r;
            float invl = 1.f / l_run[r];
            #pragma unroll
            for (int nt = 0; nt < 4; nt++) {
                int d = nt * 16 + lr;
                ob[(((size_t)b * SS + qg) * NHH + h) * DD + d] = (__bf16)(O[nt][r] * invl);
            }
        }
    } else {
        // =================== global-query pass1 path ===================
        typedef float frow68[68];
        frow68* Qs  = (frow68*)(smem);              // [16][68]
        frow68* Kt  = (frow68*)(smem + 4352);       // [64][68] Kt[d][key]
        frow68* Vs  = (frow68*)(smem + 21760);      // [64][68] Vs[key][d]
        typedef float frow17[17];
        frow17* Ssc = (frow17*)(smem + 39168);      // [64][17]
        float* m_sh  = (float*)(smem + 43520);
        float* l_sh  = m_sh + GG;
        float* al_sh = l_sh + GG;

        const int ch = blockIdx.y - NQB;
        int q_i = tid >> 5;   // query 0..15
        int g_i = tid & 31;   // group 0..31

        {   // load 16 global Q rows (2 bf16 -> f32 per thread)
            const __bf16* qp = q + (((size_t)b * SS + q_i) * NHH + h) * DD + g_i * 2;
            Qs[q_i][g_i * 2]     = (float)qp[0];
            Qs[q_i][g_i * 2 + 1] = (float)qp[1];
        }
        if (tid < GG) { m_sh[tid] = -1e30f; l_sh[tid] = 0.f; }

        float O0 = 0.f, O1 = 0.f;

        for (int t = 0; t < 4; t++) {
            int kbase = ch * 256 + t * 64;
            __syncthreads();
            {   // stage K/V tile: r = key 0..63, dq = 8-dim chunk
                int r = tid >> 3, dq = (tid & 7) * 8;
                const __bf16* kp = kg + (((size_t)b * SS + kbase + r) * NHH + h) * DD + dq;
                const __bf16* vp = vg + (((size_t)b * SS + kbase + r) * NHH + h) * DD + dq;
                bf16x8 k0 = *(const bf16x8*)kp;
                bf16x8 v0 = *(const bf16x8*)vp;
                #pragma unroll
                for (int u = 0; u < 8; u++) {
                    Kt[dq + u][r] = (float)k0[u];
                    Vs[r][dq + u] = (float)v0[u];
                }
            }
            __syncthreads();

            // scores: thread (q_i, g_i) -> keys g_i*2, g_i*2+1
            float s0 = 0.f, s1 = 0.f;
            for (int d = 0; d < 64; d++) {
                float qv = Qs[q_i][d];
                s0 += qv * Kt[d][g_i * 2];
                s1 += qv * Kt[d][g_i * 2 + 1];
            }
            Ssc[g_i * 2][q_i]     = s0;
            Ssc[g_i * 2 + 1][q_i] = s1;
            __syncthreads();

            if (tid < GG) {
                float mo = m_sh[tid], mx = mo;
                for (int kk = 0; kk < 64; kk++) mx = fmaxf(mx, Ssc[kk][tid]);
                float al = __expf(mo - mx);
                al_sh[tid] = al; m_sh[tid] = mx;
                float s = 0.f;
                for (int kk = 0; kk < 64; kk++) {
                    float p = __expf(Ssc[kk][tid] - mx);
                    Ssc[kk][tid] = p;
                    s += p;
                }
                l_sh[tid] = l_sh[tid] * al + s;
            }
            __syncthreads();

            // PV: thread (q_i, g_i) accumulates dims g_i*2, g_i*2+1
            float al = al_sh[q_i];
            O0 *= al; O1 *= al;
            for (int kk = 0; kk < 64; kk++) {
                float p = Ssc[kk][q_i];
                O0 += p * Vs[kk][g_i * 2];
                O1 += p * Vs[kk][g_i * 2 + 1];
            }
        }
        __syncthreads();

        size_t base = (((size_t)b * NHH + h) * NCH + ch) * GP_STRIDE;
        part[base + q_i * DD + g_i * 2]     = O0;
        part[base + q_i * DD + g_i * 2 + 1] = O1;
        if (tid < GG) {
            part[base + GG * DD + tid] = m_sh[tid];
            part[base + GG * DD + GG + tid] = l_sh[tid];
        }
    }
}

// ---------------------------------------------------------------------------
// Global-query attention pass 2: merge NCH chunk partials, write bf16 rows.
__global__ __launch_bounds__(64) void global_attn_combine(const float* __restrict__ part,
    __bf16* __restrict__ ob)
{
    int g = blockIdx.x, h = blockIdx.y, b = blockIdx.z;
    int d = threadIdx.x;
    size_t base0 = (((size_t)b * NHH + h) * NCH) * GP_STRIDE;
    float m[NCH], l[NCH], M = -1e30f;
    #pragma unroll
    for (int ch = 0; ch < NCH; ch++) {
        m[ch] = part[base0 + ch * GP_STRIDE + GG * DD + g];
        l[ch] = part[base0 + ch * GP_STRIDE + GG * DD + GG + g];
        M = fmaxf(M, m[ch]);
    }
    float L = 0.f, o = 0.f;
    #pragma unroll
    for (int ch = 0; ch < NCH; ch++) {
        float w = __expf(m[ch] - M);
        L += w * l[ch];
        o += w * part[base0 + ch * GP_STRIDE + g * DD + d];
    }
    ob[(((size_t)b * SS + g) * NHH + h) * DD + d] = (__bf16)(o / L);
}

// ---------------------------------------------------------------------------
// Pair head: out[row,:] = concat(x[b,i,:], x[b,j,:]) @ Wh + bh
__global__ __launch_bounds__(256) void pair_head_kernel(const float* __restrict__ x,
    const int* __restrict__ pairs, const float* __restrict__ Wh,
    const float* __restrict__ bh, float* __restrict__ out)
{
    int row = blockIdx.x;
    int b = row / PP;
    int i = pairs[row * 2 + 0];
    int j = pairs[row * 2 + 1];
    const float* xi = x + ((size_t)b * SS + i) * HH;
    const float* xj = x + ((size_t)b * SS + j) * HH;
    float acc[NLL] = {};
    for (int e = threadIdx.x; e < 2 * HH; e += 256) {
        float val = (e < HH) ? xi[e] : xj[e - HH];
        #pragma unroll
        for (int c = 0; c < NLL; c++) acc[c] += val * Wh[e * NLL + c];
    }
    __shared__ float red[NLL * 256];
    #pragma unroll
    for (int c = 0; c < NLL; c++) red[c * 256 + threadIdx.x] = acc[c];
    __syncthreads();
    for (int st = 128; st > 0; st >>= 1) {
        if (threadIdx.x < st)
            #pragma unroll
            for (int c = 0; c < NLL; c++)
                red[c * 256 + threadIdx.x] += red[c * 256 + threadIdx.x + st];
        __syncthreads();
    }
    if (threadIdx.x < NLL) out[row * NLL + threadIdx.x] = red[threadIdx.x * 256] + bh[threadIdx.x];
}

// ---------------------------------------------------------------------------
extern "C" void kernel_launch(void* const* d_in, const int* in_sizes, int n_in,
                              void* d_out, int out_size, void* d_ws, size_t ws_size,
                              hipStream_t stream)
{
    const int*   input_ids    = (const int*)d_in[0];
    const int*   pair_indices = (const int*)d_in[1];
    const float* emb   = (const float*)d_in[2];
    const float* Wq    = (const float*)d_in[3];
    const float* bq    = (const float*)d_in[4];
    const float* Wk    = (const float*)d_in[5];
    const float* bk    = (const float*)d_in[6];
    const float* Wv    = (const float*)d_in[7];
    const float* bv    = (const float*)d_in[8];
    const float* Wo    = (const float*)d_in[9];
    const float* bo    = (const float*)d_in[10];
    const float* ln1_g = (const float*)d_in[11];
    const float* ln1_b = (const float*)d_in[12];
    const float* Wf1   = (const float*)d_in[13];
    const float* bf1   = (const float*)d_in[14];
    const float* Wf2   = (const float*)d_in[15];
    const float* bf2   = (const float*)d_in[16];
    const float* ln2_g = (const float*)d_in[17];
    const float* ln2_b = (const float*)d_in[18];
    const float* Wh    = (const float*)d_in[19];
    const float* bh    = (const float*)d_in[20];

    const size_t R = (size_t)BB * SS;
    const size_t LWS = 4 * (size_t)HH * HH + 2 * (size_t)HH * FF;

    char* w = (char*)d_ws;
    float* x      = (float*)w;  w += R * HH * 4;
    float* t1     = (float*)w;  w += R * HH * 4;
    __bf16* qkv_bf = (__bf16*)w; w += 3 * R * HH * 2;
    __bf16* x_bf  = (__bf16*)w; w += R * HH * 2;
    __bf16* o_bf  = (__bf16*)w; w += R * HH * 2;
    __bf16* hb_bf = (__bf16*)w; w += R * FF * 2;
    float* bias_qkv = (float*)w; w += LL * 3 * HH * 4;
    float* gpart  = (float*)w;  w += (size_t)BB * NHH * NCH * GP_STRIDE * 4;
    __bf16* Wbf   = (__bf16*)w; w += LL * LWS * 2;
    __bf16* qb = qkv_bf;
    __bf16* kb = qkv_bf + R * HH;
    __bf16* vb = qkv_bf + 2 * R * HH;

    pack_bias_kernel<<<dim3(LL), 256, 0, stream>>>(bq, bk, bv, bias_qkv);
    size_t hh = (size_t)HH * HH, hf = (size_t)HH * FF;
    transpose_bf16_kernel<<<dim3(HH/32, HH/32, LL), 256, 0, stream>>>(Wq, Wbf,            HH, HH, hh, LWS);
    transpose_bf16_kernel<<<dim3(HH/32, HH/32, LL), 256, 0, stream>>>(Wk, Wbf + hh,       HH, HH, hh, LWS);
    transpose_bf16_kernel<<<dim3(HH/32, HH/32, LL), 256, 0, stream>>>(Wv, Wbf + 2 * hh,   HH, HH, hh, LWS);
    transpose_bf16_kernel<<<dim3(HH/32, HH/32, LL), 256, 0, stream>>>(Wo, Wbf + 3 * hh,   HH, HH, hh, LWS);
    transpose_bf16_kernel<<<dim3(FF/32, HH/32, LL), 256, 0, stream>>>(Wf1, Wbf + 4 * hh,  HH, FF, hf, LWS);
    transpose_bf16_kernel<<<dim3(HH/32, FF/32, LL), 256, 0, stream>>>(Wf2, Wbf + 4 * hh + hf, FF, HH, hf, LWS);

    embed_kernel<<<dim3((int)R), 256, 0, stream>>>(input_ids, emb, x, x_bf);

    for (int l = 0; l < LL; l++) {
        __bf16* Wl = Wbf + (size_t)l * LWS;
        const float* lbo  = bo  + (size_t)l * HH;
        const float* lg1  = ln1_g + (size_t)l * HH;  const float* lb1 = ln1_b + (size_t)l * HH;
        const float* lbf1 = bf1 + (size_t)l * FF;
        const float* lbf2 = bf2 + (size_t)l * HH;
        const float* lg2  = ln2_g + (size_t)l * HH;  const float* lb2 = ln2_b + (size_t)l * HH;

        // QKV: bf16 outputs (q pre-scaled). 64x128 tiles -> 1152 blocks.
        mfma_gemm<64,128><<<dim3(3 * HH / 128, R / 64), 256, 0, stream>>>(
            x_bf, Wl, bias_qkv + (size_t)l * 3 * HH, nullptr, qkv_bf,
            (int)R, 3 * HH, HH, 4, 0.125f);

        // band + global pass1 fused; combine merges chunk partials
        attn_fused<<<dim3(NHH, NQB + NCH, BB), 512, 0, stream>>>(qb, kb, vb, o_bf, gpart);
        global_attn_combine<<<dim3(GG, NHH, BB), 64, 0, stream>>>(gpart, o_bf);

        // attn-out: 64x64 tiles -> 768 blocks, fused bias+residual -> t1
        mfma_gemm<64,64><<<dim3(HH / 64, R / 64), 256, 0, stream>>>(
            o_bf, Wl + 3 * hh, lbo, x, t1, (int)R, HH, HH, 2, 0.f);
        ln_kernel<<<dim3((int)R), 256, 0, stream>>>(t1, lg1, lb1, x, x_bf);

        // FF1: 128x128 tiles -> 768 blocks (already 3/CU)
        mfma_gemm<128,128><<<dim3(FF / 128, R / 128), 256, 0, stream>>>(
            x_bf, Wl + 4 * hh, lbf1, nullptr, hb_bf, (int)R, FF, HH, 3, 0.f);

        // FF2: 64x64 tiles -> 768 blocks, fused bias+residual -> t1
        mfma_gemm<64,64><<<dim3(HH / 64, R / 64), 256, 0, stream>>>(
            hb_bf, Wl + 4 * hh + hf, lbf2, x, t1, (int)R, HH, FF, 2, 0.f);
        ln_kernel<<<dim3((int)R), 256, 0, stream>>>(t1, lg2, lb2, x, x_bf);
    }

    pair_head_kernel<<<dim3(BB * PP), 256, 0, stream>>>(x, pair_indices, Wh, bh, (float*)d_out);
}